// Round 16
// baseline (136.467 us; speedup 1.0000x reference)
//
#include <hip/hip_runtime.h>
#include <hip/hip_bf16.h>

typedef __hip_bfloat16 bf16;
typedef __attribute__((ext_vector_type(8))) unsigned short u16x8;
typedef __attribute__((ext_vector_type(4))) unsigned short u16x4;
typedef __attribute__((ext_vector_type(4))) float f32x4;
typedef __attribute__((ext_vector_type(8))) short bf16x8;

#define B_   64
#define NE_  256
#define NN_  1024
#define L_   512
#define HID_ 128
#define ALPHA_ 0.2f

__device__ __forceinline__ float bfu(unsigned short u){
  unsigned int x = ((unsigned int)u) << 16;
  union { unsigned int i; float f; } c; c.i = x; return c.f;
}
__device__ __forceinline__ unsigned short f2b(float f){
  bf16 h = __float2bfloat16(f);
  union { bf16 b; unsigned short u; } c; c.b = h; return c.u;
}
// chunk swizzle: involution in c for fixed r; spreads frag reads to <=2-way
__device__ __forceinline__ int swz(int r, int c){ return (c ^ (r & 3) ^ ((r >> 2) & 3)) & 3; }

// ---------------------------------------------------------------------------
// k_front: fused front-end (one launch), all phases coalesced.
// blocks [0,1024)    : adj bit-pack (r12 per-lane VALU pack, 1KB/instr loads)
// blocks [1024,2048) : layer-1 fproj (self-computed ce1/cf1/s0)
// blocks [2048,2122) : consts/W2T/pooled-zero/wcount+msum
// consts layout (floats): [0:128) ce1_1, [128:256) cf1_1, [256:384) cf2_1,
// [384:512) ce1_2, [512:640) cf1_2, [640:768) cf2_2, [768] s0_1, [769] s0_2
// ---------------------------------------------------------------------------
__global__ __launch_bounds__(256) void k_front(
    const float* __restrict__ adj,
    unsigned long long* __restrict__ ADJBb, unsigned short* __restrict__ ADJT16,
    const float* __restrict__ emb, const int* __restrict__ items,
    const float* __restrict__ w2_1, const float* __restrict__ w3_1,
    const float* __restrict__ a_1,  const float* __restrict__ a2_1,
    const float* __restrict__ wc_1,
    const float* __restrict__ w_2,
    const float* __restrict__ w2_2, const float* __restrict__ w3_2,
    const float* __restrict__ a_2,  const float* __restrict__ a2_2,
    const float* __restrict__ wc_2,
    const int* __restrict__ alias, const float* __restrict__ masks,
    float* __restrict__ w1L1, float* __restrict__ f1L1,
    unsigned short* __restrict__ YT,
    float* __restrict__ consts, unsigned short* __restrict__ W2T,
    float* __restrict__ wcount, float* __restrict__ msum,
    float* __restrict__ pooled)
{
  __shared__ __attribute__((aligned(16))) unsigned char SMEM[18944];
  const int id = blockIdx.x;
  const int t  = threadIdx.x;     // 256

  if (id < 1024) {
    // -------- adj bit-pack: coalesced loads + per-lane VALU pack ----------
    unsigned long long (*Lbits)[17] = (unsigned long long(*)[17])SMEM;
    const int b  = id & 63;              // same-batch blocks -> same XCD
    const int ec = id >> 6;              // 0..15
    const int wv = t >> 6, lane = t & 63;
    const int grp = lane >> 4;           // 0..3 (16-lane group)
    const int gl  = lane & 15;
    #pragma unroll
    for (int rr = 0; rr < 4; ++rr) {
      const int r = wv*4 + rr;           // 0..15 within chunk
      const int e = ec*16 + r;
      const float* src = adj + ((long)b*NE_ + e)*NN_;
      #pragma unroll
      for (int i = 0; i < 4; ++i) {
        f32x4 v = *(const f32x4*)(src + i*256 + lane*4);
        unsigned long long nib =
              (unsigned long long)(v[0] != 0.f)
            | ((unsigned long long)(v[1] != 0.f) << 1)
            | ((unsigned long long)(v[2] != 0.f) << 2)
            | ((unsigned long long)(v[3] != 0.f) << 3);
        unsigned long long word = nib << (gl * 4);
        #pragma unroll
        for (int s = 1; s < 16; s <<= 1)
          word |= __shfl_xor(word, s);   // OR-reduce within 16-lane group
        if (gl == 0) {
          Lbits[r][i*4 + grp] = word;
          ADJBb[((long)b*NE_ + e)*16 + i*4 + grp] = word;
        }
      }
    }
    __syncthreads();
    #pragma unroll
    for (int j = 0; j < 4; ++j) {
      int n = t + 256*j;
      int w = n >> 6, bitn = n & 63;
      unsigned int o = 0;
      #pragma unroll
      for (int rr = 0; rr < 16; ++rr)
        o |= (unsigned int)((Lbits[rr][w] >> bitn) & 1ull) << rr;
      ADJT16[((long)b*NN_ + n)*16 + ec] = (unsigned short)o;
    }
  } else if (id < 2048) {
    // -------- layer-1 fproj with self-computed consts ----------------------
    float* ce1s = (float*)SMEM;                 // 128 f
    float* cf1s = (float*)(SMEM + 512);         // 128 f
    float* s0s  = (float*)(SMEM + 1024);        // 1 f
    unsigned short (*T)[132] = (unsigned short(*)[132])(SMEM + 1056);
    {
      int rr = t & 127;
      const float* Mrow = w2_1 + rr*128;
      const float* vv = (t < 128) ? (a_1 + 128) : a2_1;
      float acc = 0.f;
      #pragma unroll 4
      for (int o = 0; o < 128; o += 4) {
        f32x4 m = *(const f32x4*)(Mrow + o);
        f32x4 x = *(const f32x4*)(vv + o);
        acc += m[0]*x[0] + m[1]*x[1] + m[2]*x[2] + m[3]*x[3];
      }
      if (t < 128) ce1s[rr] = acc; else cf1s[rr] = acc;
      if (t < 64) {
        float s = wc_1[t]*a_1[t] + wc_1[t+64]*a_1[t+64];
        #pragma unroll
        for (int sh = 32; sh > 0; sh >>= 1) s += __shfl_xor(s, sh);
        if (t == 0) s0s[0] = s;
      }
    }
    __syncthreads();
    int fid = id - 1024;
    int b = fid & 63, n0 = (fid >> 6) * 64;
    int r = t >> 2, h0 = (t & 3) * 32;
    long row = (long)b*NN_ + n0 + r;
    float s0 = s0s[0];
    float xv[32];
    const float* sp = emb + (long)items[row]*HID_ + h0;
    #pragma unroll
    for (int j = 0; j < 32; j += 4) {
      f32x4 v = *(const f32x4*)(sp + j);
      #pragma unroll
      for (int k = 0; k < 4; ++k) xv[j+k] = v[k];
    }
    float p1 = 0.f, p2 = 0.f;
    #pragma unroll
    for (int j = 0; j < 32; ++j) { p1 += xv[j]*ce1s[h0+j]; p2 += xv[j]*cf1s[h0+j]; }
    p1 += __shfl_xor(p1, 1, 4); p1 += __shfl_xor(p1, 2, 4);
    p2 += __shfl_xor(p2, 1, 4); p2 += __shfl_xor(p2, 2, 4);
    float z = p1 + s0; z = (z >= 0.f) ? z : ALPHA_*z;
    float w = __expf(z);
    if ((t & 3) == 0) { w1L1[row] = w; f1L1[row] = p2; }
    #pragma unroll
    for (int j = 0; j < 32; j += 4) {
      u16x4 o;
      #pragma unroll
      for (int k = 0; k < 4; ++k) o[k] = f2b(w * xv[j+k]);
      *(u16x4*)&T[r][h0+j] = o;
    }
    __syncthreads();
    int h = t >> 1, nh = (t & 1) * 32;
    unsigned short* dst = YT + ((long)b*HID_ + h)*NN_ + n0 + nh;
    #pragma unroll
    for (int j = 0; j < 32; j += 8) {
      u16x8 o;
      #pragma unroll
      for (int k = 0; k < 8; ++k) o[k] = T[nh+j+k][h];
      *(u16x8*)&dst[j] = o;
    }
  } else {
    int blk = id - 2048;
    float* wcs  = (float*)SMEM;
    float* red4 = (float*)(SMEM + 4096);
    if (blk < 6) {
      if (t < 128) {
        const float* M; const float* v;
        switch (blk) {
          case 0: M = w2_1; v = a_1  + 128; break;
          case 1: M = w2_1; v = a2_1;       break;
          case 2: M = w3_1; v = a2_1 + 128; break;
          case 3: M = w2_2; v = a_2  + 128; break;
          case 4: M = w2_2; v = a2_2;       break;
          default: M = w3_2; v = a2_2 + 128; break;
        }
        float acc = 0.f;
        #pragma unroll 4
        for (int o = 0; o < 128; o += 4) {
          f32x4 m = *(const f32x4*)(M + t*128 + o);
          f32x4 x = *(const f32x4*)(v + o);
          acc += m[0]*x[0] + m[1]*x[1] + m[2]*x[2] + m[3]*x[3];
        }
        consts[blk*128 + t] = acc;
      }
    } else if (blk < 8) {
      const float* wc = (blk == 6) ? wc_1 : wc_2;
      const float* a  = (blk == 6) ? a_1  : a_2;
      if (t < 64) {
        float s = wc[t]*a[t] + wc[t+64]*a[t+64];
        #pragma unroll
        for (int sh = 32; sh > 0; sh >>= 1) s += __shfl_xor(s, sh);
        if (t == 0) consts[768 + (blk - 6)] = s;
      }
    } else if (blk == 8) {
      if (t < 128) for (int k = 0; k < 128; ++k) W2T[t*128 + k] = f2b(w_2[k*128 + t]);
    } else if (blk == 9) {
      for (int i = t; i < B_*HID_; i += 256) pooled[i] = 0.f;
    } else {
      int b = blk - 10;
      #pragma unroll
      for (int j = 0; j < 4; ++j) wcs[t + j*256] = 0.f;
      __syncthreads();
      float s = 0.f;
      #pragma unroll
      for (int j = 0; j < 2; ++j) {
        int l = t + j*256;
        float m = masks[b*L_ + l];
        int idx = alias[b*L_ + l];
        atomicAdd(&wcs[idx], m*m);
        s += m;
      }
      #pragma unroll
      for (int sh = 32; sh > 0; sh >>= 1) s += __shfl_xor(s, sh);
      if ((t & 63) == 0) red4[t >> 6] = s;
      __syncthreads();
      if (t == 0) msum[b] = red4[0] + red4[1] + red4[2] + red4[3];
      #pragma unroll
      for (int j = 0; j < 4; ++j) wcount[(long)b*NN_ + t + j*256] = wcs[t + j*256];
    }
  }
}

// GEMM1 (r12 best): U = adj@Y (K=NN, bit A), double-buffered; epilogue fused.
template<int TRANSFER>
__global__ __launch_bounds__(256) void k_gemm_edge(
    const unsigned char* __restrict__ ADJ8,
    const unsigned short* __restrict__ YT,
    const float* __restrict__ w1v,
    const float* __restrict__ consts, int layer,
    const unsigned short* __restrict__ W2T,
    unsigned short* __restrict__ ET,
    float* __restrict__ f2o)
{
  __shared__ __attribute__((aligned(16))) unsigned short SM[12288];
  __shared__ float dsum[64];
  const int id = blockIdx.x;
  const int b = id & 63;                 // same-batch blocks -> same XCD
  const long e0 = (long)(id >> 6) * 64;
  const int t = threadIdx.x;
  const int lane = t & 63;
  const int w = t >> 6, wm = w >> 1, wn = w & 1;
  const int r4 = t >> 2, c4 = t & 3;
  const int lr = lane & 15, g = lane >> 4;

  f32x4 acc[2][4];
  #pragma unroll
  for (int i = 0; i < 2; ++i)
    #pragma unroll
    for (int j = 0; j < 4; ++j) acc[i][j] = (f32x4){0.f,0.f,0.f,0.f};

  const unsigned char*  Ab = ADJ8 + ((long)b*NE_ + e0 + r4)*(NN_ >> 3);
  const unsigned short* Bb = YT + (long)b*HID_*NN_;
  const float*          wb = w1v + (long)b*NN_;

  unsigned int ab; u16x8 bv0, bv1; f32x4 wv0, wv1;
  float dot = 0.f;

  auto stage = [&](int kc) {
    ab  = Ab[(kc >> 3) + c4];
    wv0 = *(const f32x4*)(wb + kc + c4*8);
    wv1 = *(const f32x4*)(wb + kc + c4*8 + 4);
    bv0 = *(const u16x8*)(Bb + (long)r4*NN_ + kc + c4*8);
    bv1 = *(const u16x8*)(Bb + (long)(64+r4)*NN_ + kc + c4*8);
  };
  auto commit = [&](int buf) {
    u16x8 av;
    #pragma unroll
    for (int j = 0; j < 8; ++j) {
      unsigned int bit = (ab >> j) & 1u;
      av[j] = bit ? (unsigned short)0x3F80 : (unsigned short)0;
      float wj = (j < 4) ? wv0[j] : wv1[j-4];
      dot += bit ? wj : 0.f;
    }
    *(u16x8*)&SM[buf*2048 + r4*32 + swz(r4,c4)*8] = av;
    *(u16x8*)&SM[4096 + buf*4096 + r4*32 + swz(r4,c4)*8] = bv0;
    *(u16x8*)&SM[4096 + buf*4096 + (64+r4)*32 + swz(64+r4,c4)*8] = bv1;
  };

  stage(0); commit(0);
  int cur = 0;
  const int NIT = NN_/32;
  for (int it = 0; it < NIT; ++it) {
    __syncthreads();
    if (it+1 < NIT) stage((it+1)*32);
    const unsigned short* AsB = &SM[cur*2048];
    const unsigned short* BsB = &SM[4096 + cur*4096];
    bf16x8 af[2], bfr[4];
    #pragma unroll
    for (int mt = 0; mt < 2; ++mt) {
      int r = wm*32 + mt*16 + lr;
      af[mt] = *(const bf16x8*)&AsB[r*32 + swz(r,g)*8];
    }
    #pragma unroll
    for (int nt = 0; nt < 4; ++nt) {
      int n = wn*64 + nt*16 + lr;
      bfr[nt] = *(const bf16x8*)&BsB[n*32 + swz(n,g)*8];
    }
    #pragma unroll
    for (int mt = 0; mt < 2; ++mt)
      #pragma unroll
      for (int nt = 0; nt < 4; ++nt)
        acc[mt][nt] = __builtin_amdgcn_mfma_f32_16x16x32_bf16(af[mt], bfr[nt], acc[mt][nt], 0, 0, 0);
    if (it+1 < NIT) { commit(cur^1); cur ^= 1; }
  }
  dot += __shfl_down(dot, 2, 4); dot += __shfl_down(dot, 1, 4);
  if ((lane & 3) == 0) dsum[r4] = dot;
  __syncthreads();   // frags read; dsum ready; SM reusable as U
  #pragma unroll
  for (int mt = 0; mt < 2; ++mt)
    #pragma unroll
    for (int nt = 0; nt < 4; ++nt) {
      int col = wn*64 + nt*16 + lr;
      #pragma unroll
      for (int q = 0; q < 4; ++q) {
        int rl = wm*32 + mt*16 + g*4 + q;
        SM[rl*136 + col] = f2b(acc[mt][nt][q] / dsum[rl]);
      }
    }
  __syncthreads();
  if (TRANSFER) {
    f32x4 acc2[2][4];
    #pragma unroll
    for (int i = 0; i < 2; ++i)
      #pragma unroll
      for (int j = 0; j < 4; ++j) acc2[i][j] = (f32x4){0.f,0.f,0.f,0.f};
    #pragma unroll
    for (int kc2 = 0; kc2 < 4; ++kc2) {
      bf16x8 af[2], bfr[4];
      #pragma unroll
      for (int mt = 0; mt < 2; ++mt) {
        int r = wm*32 + mt*16 + lr;
        af[mt] = *(const bf16x8*)&SM[r*136 + kc2*32 + g*8];
      }
      #pragma unroll
      for (int nt = 0; nt < 4; ++nt) {
        int n = wn*64 + nt*16 + lr;
        bfr[nt] = *(const bf16x8*)(W2T + n*128 + kc2*32 + g*8);
      }
      #pragma unroll
      for (int mt = 0; mt < 2; ++mt)
        #pragma unroll
        for (int nt = 0; nt < 4; ++nt)
          acc2[mt][nt] = __builtin_amdgcn_mfma_f32_16x16x32_bf16(af[mt], bfr[nt], acc2[mt][nt], 0, 0, 0);
    }
    __syncthreads();
    #pragma unroll
    for (int mt = 0; mt < 2; ++mt)
      #pragma unroll
      for (int nt = 0; nt < 4; ++nt) {
        int col = wn*64 + nt*16 + lr;
        #pragma unroll
        for (int q = 0; q < 4; ++q) {
          int rl = wm*32 + mt*16 + g*4 + q;
          SM[rl*136 + col] = f2b(acc2[mt][nt][q]);
        }
      }
    __syncthreads();
  }
  // f2 = edge . cf2
  {
    const float* cf2 = consts + layer*384 + 256;
    int r = t >> 2, h0 = (t & 3) * 32;
    float p = 0.f;
    #pragma unroll
    for (int j = 0; j < 32; ++j) p += bfu(SM[r*136 + h0 + j]) * cf2[h0 + j];
    p += __shfl_down(p, 2, 4); p += __shfl_down(p, 1, 4);
    if ((t & 3) == 0) f2o[(long)b*NE_ + e0 + r] = p;
  }
  // ET[b][h][e] transposed write
  {
    int h = t >> 1, eh = (t & 1) * 32;
    unsigned short* dst = ET + ((long)b*HID_ + h)*NE_ + e0 + eh;
    #pragma unroll
    for (int j = 0; j < 32; j += 8) {
      u16x8 o;
      #pragma unroll
      for (int k = 0; k < 8; ++k) o[k] = SM[(eh+j+k)*136 + h];
      *(u16x8*)&dst[j] = o;
    }
  }
}

// GEMM2 (r12 best): A = bit*exp(leaky(f1+f2)) on the fly; C = (A@edge)/rowsum
// EPI 1: elu + fused next-layer proj (w1/f1/YT). EPI 2: pooled col-sums.
template<int EPI>
__global__ __launch_bounds__(256, 2) void k_gemm_att(
    const unsigned char* __restrict__ ADJ8,
    const unsigned short* __restrict__ ET,
    const float* __restrict__ f1v, const float* __restrict__ f2v,
    const float* __restrict__ consts,
    unsigned short* __restrict__ YTout, float* __restrict__ w1o, float* __restrict__ f1o,
    const float* __restrict__ wcount, float* __restrict__ pooled)
{
  __shared__ __attribute__((aligned(16))) unsigned short SM[12288];
  __shared__ float dsum[64];
  __shared__ float colsum[128];
  __shared__ float wrow[64];
  const int id = blockIdx.x;
  const int b = id & 63;                 // same-batch blocks -> same XCD
  const long m0 = (long)(id >> 6) * 64;
  const int t = threadIdx.x;
  const int lane = t & 63;
  const int w = t >> 6, wm = w >> 1, wn = w & 1;
  const int r4 = t >> 2, c4 = t & 3;
  const int lr = lane & 15, g = lane >> 4;

  f32x4 acc[2][4];
  #pragma unroll
  for (int i = 0; i < 2; ++i)
    #pragma unroll
    for (int j = 0; j < 4; ++j) acc[i][j] = (f32x4){0.f,0.f,0.f,0.f};

  const float f1r = f1v[(long)b*NN_ + m0 + r4];
  const unsigned char*  Ab = ADJ8 + ((long)b*NN_ + m0 + r4)*(NE_ >> 3);
  const unsigned short* Bb = ET + (long)b*HID_*NE_;
  const float* f2p = f2v + (long)b*NE_;

  unsigned int ab; u16x8 bv0, bv1; f32x4 fv0, fv1;
  float dot = 0.f;

  auto stage = [&](int kc) {
    ab  = Ab[(kc >> 3) + c4];
    fv0 = *(const f32x4*)(f2p + kc + c4*8);
    fv1 = *(const f32x4*)(f2p + kc + c4*8 + 4);
    bv0 = *(const u16x8*)(Bb + (long)r4*NE_ + kc + c4*8);
    bv1 = *(const u16x8*)(Bb + (long)(64+r4)*NE_ + kc + c4*8);
  };
  auto commit = [&](int buf) {
    u16x8 av;
    #pragma unroll
    for (int j = 0; j < 8; ++j) {
      unsigned int bit = (ab >> j) & 1u;
      float z = f1r + ((j < 4) ? fv0[j] : fv1[j-4]);
      z = (z >= 0.f) ? z : ALPHA_ * z;
      float wt = bit ? __expf(z) : 0.f;
      unsigned short us = f2b(wt);
      av[j] = us; dot += bfu(us);
    }
    *(u16x8*)&SM[buf*2048 + r4*32 + swz(r4,c4)*8] = av;
    *(u16x8*)&SM[4096 + buf*4096 + r4*32 + swz(r4,c4)*8] = bv0;
    *(u16x8*)&SM[4096 + buf*4096 + (64+r4)*32 + swz(64+r4,c4)*8] = bv1;
  };

  stage(0); commit(0);
  int cur = 0;
  const int NIT = NE_/32;
  for (int it = 0; it < NIT; ++it) {
    __syncthreads();
    if (it+1 < NIT) stage((it+1)*32);
    const unsigned short* AsB = &SM[cur*2048];
    const unsigned short* BsB = &SM[4096 + cur*4096];
    bf16x8 af[2], bfr[4];
    #pragma unroll
    for (int mt = 0; mt < 2; ++mt) {
      int r = wm*32 + mt*16 + lr;
      af[mt] = *(const bf16x8*)&AsB[r*32 + swz(r,g)*8];
    }
    #pragma unroll
    for (int nt = 0; nt < 4; ++nt) {
      int n = wn*64 + nt*16 + lr;
      bfr[nt] = *(const bf16x8*)&BsB[n*32 + swz(n,g)*8];
    }
    #pragma unroll
    for (int mt = 0; mt < 2; ++mt)
      #pragma unroll
      for (int nt = 0; nt < 4; ++nt)
        acc[mt][nt] = __builtin_amdgcn_mfma_f32_16x16x32_bf16(af[mt], bfr[nt], acc[mt][nt], 0, 0, 0);
    if (it+1 < NIT) { commit(cur^1); cur ^= 1; }
  }
  dot += __shfl_down(dot, 2, 4); dot += __shfl_down(dot, 1, 4);
  if ((lane & 3) == 0) dsum[r4] = dot;
  if (EPI == 2 && t < 128) colsum[t] = 0.f;
  __syncthreads();

  if (EPI == 1) {
    // x2 = elu(node) -> LDS U[64][136]
    #pragma unroll
    for (int mt = 0; mt < 2; ++mt)
      #pragma unroll
      for (int nt = 0; nt < 4; ++nt) {
        int col = wn*64 + nt*16 + lr;
        #pragma unroll
        for (int q = 0; q < 4; ++q) {
          int rl = wm*32 + mt*16 + g*4 + q;
          float v = acc[mt][nt][q] / dsum[rl];
          v = (v > 0.f) ? v : expm1f(v);
          SM[rl*136 + col] = f2b(v);
        }
      }
    __syncthreads();
    // fused layer-2 proj: row dots with ce1_2/cf1_2
    {
      const float* ce1 = consts + 384;
      const float* cf1 = consts + 512;
      int r = t >> 2, h0 = (t & 3) * 32;
      float p1 = 0.f, p2 = 0.f;
      #pragma unroll
      for (int j = 0; j < 32; ++j) {
        float xv = bfu(SM[r*136 + h0 + j]);
        p1 += xv * ce1[h0 + j];
        p2 += xv * cf1[h0 + j];
      }
      p1 += __shfl_down(p1, 2, 4); p1 += __shfl_down(p1, 1, 4);
      p2 += __shfl_down(p2, 2, 4); p2 += __shfl_down(p2, 1, 4);
      if ((t & 3) == 0) {
        float z = p1 + consts[769];
        z = (z >= 0.f) ? z : ALPHA_ * z;
        float wv = __expf(z);
        wrow[r] = wv;
        w1o[(long)b*NN_ + m0 + r] = wv;
        f1o[(long)b*NN_ + m0 + r] = p2;
      }
    }
    __syncthreads();
    // YT[b][h][n] = bf16(w1*x2) transposed write
    {
      int h = t >> 1, nh = (t & 1) * 32;
      unsigned short* dst = YTout + ((long)b*HID_ + h)*NN_ + m0 + nh;
      #pragma unroll
      for (int j = 0; j < 32; j += 8) {
        u16x8 o;
        #pragma unroll
        for (int k = 0; k < 8; ++k) {
          int rr = nh + j + k;
          o[k] = f2b(wrow[rr] * bfu(SM[rr*136 + h]));
        }
        *(u16x8*)&dst[j] = o;
      }
    }
  } else {
    float psum[4] = {0.f, 0.f, 0.f, 0.f};
    #pragma unroll
    for (int mt = 0; mt < 2; ++mt)
      #pragma unroll
      for (int q = 0; q < 4; ++q) {
        int rl = wm*32 + mt*16 + g*4 + q;
        float wc = wcount[(long)b*NN_ + m0 + rl];
        float inv = wc / dsum[rl];
        #pragma unroll
        for (int nt = 0; nt < 4; ++nt) psum[nt] += inv * acc[mt][nt][q];
      }
    #pragma unroll
    for (int nt = 0; nt < 4; ++nt) atomicAdd(&colsum[wn*64 + nt*16 + lr], psum[nt]);
    __syncthreads();
    if (t < 128) atomicAdd(&pooled[(long)b*HID_ + t], colsum[t]);
  }
}

__global__ void k_ln(const float* __restrict__ pooled, const float* __restrict__ msum,
                     const float* __restrict__ ln_g, const float* __restrict__ ln_b,
                     float* __restrict__ out)
{
  int b = blockIdx.x, t = threadIdx.x;   // 128
  __shared__ float sr[2];
  float bv = pooled[b*HID_ + t] / msum[b];
  int lane = t & 63;
  float p = bv;
  #pragma unroll
  for (int s = 32; s > 0; s >>= 1) p += __shfl_xor(p, s);
  if (lane == 0) sr[t >> 6] = p;
  __syncthreads();
  float mu = (sr[0] + sr[1]) * (1.f / HID_);
  float dv = bv - mu;
  p = dv * dv;
  #pragma unroll
  for (int s = 32; s > 0; s >>= 1) p += __shfl_xor(p, s);
  __syncthreads();
  if (lane == 0) sr[t >> 6] = p;
  __syncthreads();
  float var = (sr[0] + sr[1]) * (1.f / HID_);
  out[b*HID_ + t] = dv / sqrtf(var + 1e-6f) * ln_g[t] + ln_b[t];
}

extern "C" void kernel_launch(void* const* d_in, const int* in_sizes, int n_in,
                              void* d_out, int out_size, void* d_ws, size_t ws_size,
                              hipStream_t stream)
{
  const int*   items = (const int*)d_in[0];
  const int*   alias = (const int*)d_in[1];
  const float* masks = (const float*)d_in[2];
  const float* adj   = (const float*)d_in[3];
  const float* emb   = (const float*)d_in[4];
  const float* w2_1  = (const float*)d_in[5];
  const float* w3_1  = (const float*)d_in[6];
  const float* a_1   = (const float*)d_in[7];
  const float* a2_1  = (const float*)d_in[8];
  const float* wc_1  = (const float*)d_in[9];
  const float* w_2   = (const float*)d_in[10];
  const float* w2_2  = (const float*)d_in[11];
  const float* w3_2  = (const float*)d_in[12];
  const float* a_2   = (const float*)d_in[13];
  const float* a2_2  = (const float*)d_in[14];
  const float* wc_2  = (const float*)d_in[15];
  const float* ln_g  = (const float*)d_in[16];
  const float* ln_b  = (const float*)d_in[17];
  float* out = (float*)d_out;

  char* ws = (char*)d_ws;
  size_t off = 0;
  auto alloc = [&](size_t bytes) -> void* {
    void* p = ws + off; off += (bytes + 255) / 256 * 256; return p;
  };
  unsigned long long* ADJBb = (unsigned long long*)alloc((size_t)B_*NE_*(NN_/8));
  unsigned short*     ADJT16= (unsigned short*)    alloc((size_t)B_*NN_*(NE_/8));
  unsigned short* YT   = (unsigned short*)alloc((size_t)B_*HID_*NN_*2);
  unsigned short* ET   = (unsigned short*)alloc((size_t)B_*HID_*NE_*2);
  float* wcount= (float*)alloc((size_t)B_*NN_*4);
  float* pooled= (float*)alloc((size_t)B_*HID_*4);
  float* w1L1  = (float*)alloc((size_t)B_*NN_*4);
  float* f1L1  = (float*)alloc((size_t)B_*NN_*4);
  float* w1L2  = (float*)alloc((size_t)B_*NN_*4);
  float* f1L2  = (float*)alloc((size_t)B_*NN_*4);
  float* f2    = (float*)alloc((size_t)B_*NE_*4);
  float* msum  = (float*)alloc(B_*4);
  float* consts= (float*)alloc(772*4);
  unsigned short* W2T = (unsigned short*)alloc((size_t)HID_*HID_*2);
  if (off > ws_size) return;

  // ---------------- fused front-end (1 launch, fast patterns) ----------------
  k_front<<<2122, 256, 0, stream>>>(adj, ADJBb, ADJT16, emb, items,
        w2_1, w3_1, a_1, a2_1, wc_1, w_2, w2_2, w3_2, a_2, a2_2, wc_2,
        alias, masks, w1L1, f1L1, YT, consts, W2T, wcount, msum, pooled);

  // ---------------- layer 1 ----------------
  k_gemm_edge<0><<<B_*(NE_/64), 256, 0, stream>>>((const unsigned char*)ADJBb, YT, w1L1,
        consts, 0, W2T, ET, f2);
  k_gemm_att<1><<<B_*(NN_/64), 256, 0, stream>>>((const unsigned char*)ADJT16, ET, f1L1, f2,
        consts, YT, w1L2, f1L2, nullptr, nullptr);

  // ---------------- layer 2 ----------------
  k_gemm_edge<1><<<B_*(NE_/64), 256, 0, stream>>>((const unsigned char*)ADJBb, YT, w1L2,
        consts, 1, W2T, ET, f2);
  k_gemm_att<2><<<B_*(NN_/64), 256, 0, stream>>>((const unsigned char*)ADJT16, ET, f1L2, f2,
        consts, nullptr, nullptr, nullptr, wcount, pooled);

  // ---------------- layernorm ----------------
  k_ln<<<B_, HID_, 0, stream>>>(pooled, msum, ln_g, ln_b, out);
}

// Round 17
// 120.894 us; speedup vs baseline: 1.1288x; 1.1288x over previous
//
#include <hip/hip_runtime.h>
#include <hip/hip_bf16.h>

typedef __hip_bfloat16 bf16;
typedef __attribute__((ext_vector_type(8))) unsigned short u16x8;
typedef __attribute__((ext_vector_type(4))) unsigned short u16x4;
typedef __attribute__((ext_vector_type(4))) float f32x4;
typedef __attribute__((ext_vector_type(8))) short bf16x8;

#define B_   64
#define NE_  256
#define NN_  1024
#define L_   512
#define HID_ 128
#define ALPHA_ 0.2f

__device__ __forceinline__ float bfu(unsigned short u){
  unsigned int x = ((unsigned int)u) << 16;
  union { unsigned int i; float f; } c; c.i = x; return c.f;
}
__device__ __forceinline__ unsigned short f2b(float f){
  bf16 h = __float2bfloat16(f);
  union { bf16 b; unsigned short u; } c; c.b = h; return c.u;
}
// chunk swizzle: involution in c for fixed r; spreads frag reads to <=2-way
__device__ __forceinline__ int swz(int r, int c){ return (c ^ (r & 3) ^ ((r >> 2) & 3)) & 3; }

// ---------------------------------------------------------------------------
// k_small: consts + W2T + wcount/msum + zero pooled (74 blocks)
// consts layout (floats): [0:128) ce1_1, [128:256) cf1_1, [256:384) cf2_1,
// [384:512) ce1_2, [512:640) cf1_2, [640:768) cf2_2, [768] s0_1, [769] s0_2
// ---------------------------------------------------------------------------
__global__ void k_small(const float* __restrict__ w2_1, const float* __restrict__ w3_1,
                        const float* __restrict__ a_1,  const float* __restrict__ a2_1,
                        const float* __restrict__ wc_1,
                        const float* __restrict__ w2_2, const float* __restrict__ w3_2,
                        const float* __restrict__ a_2,  const float* __restrict__ a2_2,
                        const float* __restrict__ wc_2,
                        const float* __restrict__ w_2,
                        const int* __restrict__ alias, const float* __restrict__ masks,
                        float* __restrict__ consts, unsigned short* __restrict__ W2T,
                        float* __restrict__ wcount, float* __restrict__ msum,
                        float* __restrict__ pooled)
{
  __shared__ float wcs[1024];
  __shared__ float red4[4];
  int blk = blockIdx.x, t = threadIdx.x; // 256
  if (blk < 6) {
    if (t < 128) {
      const float* M; const float* v;
      switch (blk) {
        case 0: M = w2_1; v = a_1  + 128; break;
        case 1: M = w2_1; v = a2_1;       break;
        case 2: M = w3_1; v = a2_1 + 128; break;
        case 3: M = w2_2; v = a_2  + 128; break;
        case 4: M = w2_2; v = a2_2;       break;
        default: M = w3_2; v = a2_2 + 128; break;
      }
      float acc = 0.f;
      #pragma unroll 4
      for (int o = 0; o < 128; o += 4) {
        f32x4 m = *(const f32x4*)(M + t*128 + o);
        f32x4 x = *(const f32x4*)(v + o);
        acc += m[0]*x[0] + m[1]*x[1] + m[2]*x[2] + m[3]*x[3];
      }
      consts[blk*128 + t] = acc;
    }
  } else if (blk < 8) {
    const float* wc = (blk == 6) ? wc_1 : wc_2;
    const float* a  = (blk == 6) ? a_1  : a_2;
    if (t < 64) {
      float s = wc[t]*a[t] + wc[t+64]*a[t+64];
      #pragma unroll
      for (int sh = 32; sh > 0; sh >>= 1) s += __shfl_xor(s, sh);
      if (t == 0) consts[768 + (blk - 6)] = s;
    }
  } else if (blk == 8) {
    if (t < 128) for (int k = 0; k < 128; ++k) W2T[t*128 + k] = f2b(w_2[k*128 + t]);
  } else if (blk == 9) {
    for (int i = t; i < B_*HID_; i += 256) pooled[i] = 0.f;
  } else {
    int b = blk - 10;
    #pragma unroll
    for (int j = 0; j < 4; ++j) wcs[t + j*256] = 0.f;
    __syncthreads();
    float s = 0.f;
    #pragma unroll
    for (int j = 0; j < 2; ++j) {
      int l = t + j*256;
      float m = masks[b*L_ + l];
      int idx = alias[b*L_ + l];
      atomicAdd(&wcs[idx], m*m);
      s += m;
    }
    #pragma unroll
    for (int sh = 32; sh > 0; sh >>= 1) s += __shfl_xor(s, sh);
    if ((t & 63) == 0) red4[t >> 6] = s;
    __syncthreads();
    if (t == 0) msum[b] = red4[0] + red4[1] + red4[2] + red4[3];
    #pragma unroll
    for (int j = 0; j < 4; ++j) wcount[(long)b*NN_ + t + j*256] = wcs[t + j*256];
  }
}

// ---------------------------------------------------------------------------
// k_prep: coalesced loads + per-lane VALU bit-pack (r12 best).
// ---------------------------------------------------------------------------
__global__ __launch_bounds__(256) void k_prep(
    const float* __restrict__ adj,
    unsigned long long* __restrict__ ADJBb,
    unsigned short* __restrict__ ADJT16)
{
  __shared__ unsigned long long Lbits[16][17];
  const int id = blockIdx.x;           // B_ * 16 blocks
  const int b  = id & 63;              // same-batch blocks -> same XCD
  const int ec = id >> 6;              // 0..15
  const int t  = threadIdx.x;          // 256
  const int wv = t >> 6, lane = t & 63;
  const int grp = lane >> 4;           // 0..3 (16-lane group)
  const int gl  = lane & 15;

  #pragma unroll
  for (int rr = 0; rr < 4; ++rr) {
    const int r = wv*4 + rr;           // 0..15 within chunk
    const int e = ec*16 + r;
    const float* src = adj + ((long)b*NE_ + e)*NN_;
    #pragma unroll
    for (int i = 0; i < 4; ++i) {
      f32x4 v = *(const f32x4*)(src + i*256 + lane*4);
      unsigned long long nib =
            (unsigned long long)(v[0] != 0.f)
          | ((unsigned long long)(v[1] != 0.f) << 1)
          | ((unsigned long long)(v[2] != 0.f) << 2)
          | ((unsigned long long)(v[3] != 0.f) << 3);
      unsigned long long word = nib << (gl * 4);
      #pragma unroll
      for (int s = 1; s < 16; s <<= 1)
        word |= __shfl_xor(word, s);   // OR-reduce within 16-lane group
      if (gl == 0) {
        Lbits[r][i*4 + grp] = word;
        ADJBb[((long)b*NE_ + e)*16 + i*4 + grp] = word;
      }
    }
  }
  __syncthreads();
  #pragma unroll
  for (int j = 0; j < 4; ++j) {
    int n = t + 256*j;
    int w = n >> 6, bitn = n & 63;
    unsigned int o = 0;
    #pragma unroll
    for (int rr = 0; rr < 16; ++rr)
      o |= (unsigned int)((Lbits[rr][w] >> bitn) & 1ull) << rr;
    ADJT16[((long)b*NN_ + n)*16 + ec] = (unsigned short)o;
  }
}

// layer-1 fused: e1/f1 row-dots + w1=exp(e1) + YT[b][h][n] = bf16(w1*x) transposed
__global__ void k_fproj(const float* __restrict__ emb, const int* __restrict__ gitems,
                        const float* __restrict__ consts,
                        float* __restrict__ w1, float* __restrict__ f1,
                        unsigned short* __restrict__ YT)
{
  __shared__ float ce1s[128], cf1s[128];
  __shared__ __attribute__((aligned(16))) unsigned short T[64][132];
  int b = blockIdx.y, n0 = blockIdx.x * 64, t = threadIdx.x;  // 256
  if (t < 128) { ce1s[t] = consts[t]; cf1s[t] = consts[128 + t]; }
  __syncthreads();
  int r = t >> 2, h0 = (t & 3) * 32;
  long row = (long)b*NN_ + n0 + r;
  float s0 = consts[768];
  float xv[32];
  const float* sp = emb + (long)gitems[row]*HID_ + h0;
  #pragma unroll
  for (int j = 0; j < 32; j += 4) {
    f32x4 v = *(const f32x4*)(sp + j);
    #pragma unroll
    for (int k = 0; k < 4; ++k) xv[j+k] = v[k];
  }
  float p1 = 0.f, p2 = 0.f;
  #pragma unroll
  for (int j = 0; j < 32; ++j) { p1 += xv[j]*ce1s[h0+j]; p2 += xv[j]*cf1s[h0+j]; }
  p1 += __shfl_xor(p1, 1, 4); p1 += __shfl_xor(p1, 2, 4);
  p2 += __shfl_xor(p2, 1, 4); p2 += __shfl_xor(p2, 2, 4);
  float z = p1 + s0; z = (z >= 0.f) ? z : ALPHA_*z;
  float w = __expf(z);
  if ((t & 3) == 0) { w1[row] = w; f1[row] = p2; }
  #pragma unroll
  for (int j = 0; j < 32; j += 4) {
    u16x4 o;
    #pragma unroll
    for (int k = 0; k < 4; ++k) o[k] = f2b(w * xv[j+k]);
    *(u16x4*)&T[r][h0+j] = o;
  }
  __syncthreads();
  int h = t >> 1, nh = (t & 1) * 32;
  unsigned short* dst = YT + ((long)b*HID_ + h)*NN_ + n0 + nh;
  #pragma unroll
  for (int j = 0; j < 32; j += 8) {
    u16x8 o;
    #pragma unroll
    for (int k = 0; k < 8; ++k) o[k] = T[nh+j+k][h];
    *(u16x8*)&dst[j] = o;
  }
}

// GEMM1: U = adj@Y (K=NN, bit A), 2-deep register prefetch + dbuf LDS.
template<int TRANSFER>
__global__ __launch_bounds__(256) void k_gemm_edge(
    const unsigned char* __restrict__ ADJ8,
    const unsigned short* __restrict__ YT,
    const float* __restrict__ w1v,
    const float* __restrict__ consts, int layer,
    const unsigned short* __restrict__ W2T,
    unsigned short* __restrict__ ET,
    float* __restrict__ f2o)
{
  __shared__ __attribute__((aligned(16))) unsigned short SM[12288];
  __shared__ float dsum[64];
  const int id = blockIdx.x;
  const int b = id & 63;                 // same-batch blocks -> same XCD
  const long e0 = (long)(id >> 6) * 64;
  const int t = threadIdx.x;
  const int lane = t & 63;
  const int w = t >> 6, wm = w >> 1, wn = w & 1;
  const int r4 = t >> 2, c4 = t & 3;
  const int lr = lane & 15, g = lane >> 4;

  f32x4 acc[2][4];
  #pragma unroll
  for (int i = 0; i < 2; ++i)
    #pragma unroll
    for (int j = 0; j < 4; ++j) acc[i][j] = (f32x4){0.f,0.f,0.f,0.f};

  const unsigned char*  Ab = ADJ8 + ((long)b*NE_ + e0 + r4)*(NN_ >> 3);
  const unsigned short* Bb = YT + (long)b*HID_*NN_;
  const float*          wb = w1v + (long)b*NN_;

  unsigned int ab[2]; u16x8 bv0[2], bv1[2]; f32x4 wv0[2], wv1[2];
  float dot = 0.f;

  auto stage = [&](int kc, int s) {
    ab[s]  = Ab[(kc >> 3) + c4];
    wv0[s] = *(const f32x4*)(wb + kc + c4*8);
    wv1[s] = *(const f32x4*)(wb + kc + c4*8 + 4);
    bv0[s] = *(const u16x8*)(Bb + (long)r4*NN_ + kc + c4*8);
    bv1[s] = *(const u16x8*)(Bb + (long)(64+r4)*NN_ + kc + c4*8);
  };
  auto commit = [&](int s, int buf) {
    u16x8 av;
    #pragma unroll
    for (int j = 0; j < 8; ++j) {
      unsigned int bit = (ab[s] >> j) & 1u;
      av[j] = bit ? (unsigned short)0x3F80 : (unsigned short)0;
      float wj = (j < 4) ? wv0[s][j] : wv1[s][j-4];
      dot += bit ? wj : 0.f;
    }
    *(u16x8*)&SM[buf*2048 + r4*32 + swz(r4,c4)*8] = av;
    *(u16x8*)&SM[4096 + buf*4096 + r4*32 + swz(r4,c4)*8] = bv0[s];
    *(u16x8*)&SM[4096 + buf*4096 + (64+r4)*32 + swz(64+r4,c4)*8] = bv1[s];
  };

  const int NIT = NN_/32;
  stage(0, 0);
  stage(32, 1);
  commit(0, 0);
  int cur = 0;
  for (int it = 0; it < NIT; ++it) {
    __syncthreads();
    if (it+2 < NIT) stage((it+2)*32, it & 1);
    const unsigned short* AsB = &SM[cur*2048];
    const unsigned short* BsB = &SM[4096 + cur*4096];
    bf16x8 af[2], bfr[4];
    #pragma unroll
    for (int mt = 0; mt < 2; ++mt) {
      int r = wm*32 + mt*16 + lr;
      af[mt] = *(const bf16x8*)&AsB[r*32 + swz(r,g)*8];
    }
    #pragma unroll
    for (int nt = 0; nt < 4; ++nt) {
      int n = wn*64 + nt*16 + lr;
      bfr[nt] = *(const bf16x8*)&BsB[n*32 + swz(n,g)*8];
    }
    #pragma unroll
    for (int mt = 0; mt < 2; ++mt)
      #pragma unroll
      for (int nt = 0; nt < 4; ++nt)
        acc[mt][nt] = __builtin_amdgcn_mfma_f32_16x16x32_bf16(af[mt], bfr[nt], acc[mt][nt], 0, 0, 0);
    if (it+1 < NIT) { commit((it+1) & 1, cur^1); cur ^= 1; }
  }
  dot += __shfl_down(dot, 2, 4); dot += __shfl_down(dot, 1, 4);
  if ((lane & 3) == 0) dsum[r4] = dot;
  __syncthreads();   // frags read; dsum ready; SM reusable as U
  #pragma unroll
  for (int mt = 0; mt < 2; ++mt)
    #pragma unroll
    for (int nt = 0; nt < 4; ++nt) {
      int col = wn*64 + nt*16 + lr;
      #pragma unroll
      for (int q = 0; q < 4; ++q) {
        int rl = wm*32 + mt*16 + g*4 + q;
        SM[rl*136 + col] = f2b(acc[mt][nt][q] / dsum[rl]);
      }
    }
  __syncthreads();
  if (TRANSFER) {
    f32x4 acc2[2][4];
    #pragma unroll
    for (int i = 0; i < 2; ++i)
      #pragma unroll
      for (int j = 0; j < 4; ++j) acc2[i][j] = (f32x4){0.f,0.f,0.f,0.f};
    #pragma unroll
    for (int kc2 = 0; kc2 < 4; ++kc2) {
      bf16x8 af[2], bfr[4];
      #pragma unroll
      for (int mt = 0; mt < 2; ++mt) {
        int r = wm*32 + mt*16 + lr;
        af[mt] = *(const bf16x8*)&SM[r*136 + kc2*32 + g*8];
      }
      #pragma unroll
      for (int nt = 0; nt < 4; ++nt) {
        int n = wn*64 + nt*16 + lr;
        bfr[nt] = *(const bf16x8*)(W2T + n*128 + kc2*32 + g*8);
      }
      #pragma unroll
      for (int mt = 0; mt < 2; ++mt)
        #pragma unroll
        for (int nt = 0; nt < 4; ++nt)
          acc2[mt][nt] = __builtin_amdgcn_mfma_f32_16x16x32_bf16(af[mt], bfr[nt], acc2[mt][nt], 0, 0, 0);
    }
    __syncthreads();
    #pragma unroll
    for (int mt = 0; mt < 2; ++mt)
      #pragma unroll
      for (int nt = 0; nt < 4; ++nt) {
        int col = wn*64 + nt*16 + lr;
        #pragma unroll
        for (int q = 0; q < 4; ++q) {
          int rl = wm*32 + mt*16 + g*4 + q;
          SM[rl*136 + col] = f2b(acc2[mt][nt][q]);
        }
      }
    __syncthreads();
  }
  // f2 = edge . cf2
  {
    const float* cf2 = consts + layer*384 + 256;
    int r = t >> 2, h0 = (t & 3) * 32;
    float p = 0.f;
    #pragma unroll
    for (int j = 0; j < 32; ++j) p += bfu(SM[r*136 + h0 + j]) * cf2[h0 + j];
    p += __shfl_down(p, 2, 4); p += __shfl_down(p, 1, 4);
    if ((t & 3) == 0) f2o[(long)b*NE_ + e0 + r] = p;
  }
  // ET[b][h][e] transposed write
  {
    int h = t >> 1, eh = (t & 1) * 32;
    unsigned short* dst = ET + ((long)b*HID_ + h)*NE_ + e0 + eh;
    #pragma unroll
    for (int j = 0; j < 32; j += 8) {
      u16x8 o;
      #pragma unroll
      for (int k = 0; k < 8; ++k) o[k] = SM[(eh+j+k)*136 + h];
      *(u16x8*)&dst[j] = o;
    }
  }
}

// GEMM2: A = bit*exp(leaky(f1+f2)) on the fly; 2-deep prefetch; C = (A@edge)/rowsum
// EPI 1: elu + fused next-layer proj (w1/f1/YT). EPI 2: pooled col-sums.
template<int EPI>
__global__ __launch_bounds__(256, 2) void k_gemm_att(
    const unsigned char* __restrict__ ADJ8,
    const unsigned short* __restrict__ ET,
    const float* __restrict__ f1v, const float* __restrict__ f2v,
    const float* __restrict__ consts,
    unsigned short* __restrict__ YTout, float* __restrict__ w1o, float* __restrict__ f1o,
    const float* __restrict__ wcount, float* __restrict__ pooled)
{
  __shared__ __attribute__((aligned(16))) unsigned short SM[12288];
  __shared__ float dsum[64];
  __shared__ float colsum[128];
  __shared__ float wrow[64];
  const int id = blockIdx.x;
  const int b = id & 63;                 // same-batch blocks -> same XCD
  const long m0 = (long)(id >> 6) * 64;
  const int t = threadIdx.x;
  const int lane = t & 63;
  const int w = t >> 6, wm = w >> 1, wn = w & 1;
  const int r4 = t >> 2, c4 = t & 3;
  const int lr = lane & 15, g = lane >> 4;

  f32x4 acc[2][4];
  #pragma unroll
  for (int i = 0; i < 2; ++i)
    #pragma unroll
    for (int j = 0; j < 4; ++j) acc[i][j] = (f32x4){0.f,0.f,0.f,0.f};

  const float f1r = f1v[(long)b*NN_ + m0 + r4];
  const unsigned char*  Ab = ADJ8 + ((long)b*NN_ + m0 + r4)*(NE_ >> 3);
  const unsigned short* Bb = ET + (long)b*HID_*NE_;
  const float* f2p = f2v + (long)b*NE_;

  unsigned int ab[2]; u16x8 bv0[2], bv1[2]; f32x4 fv0[2], fv1[2];
  float dot = 0.f;

  auto stage = [&](int kc, int s) {
    ab[s]  = Ab[(kc >> 3) + c4];
    fv0[s] = *(const f32x4*)(f2p + kc + c4*8);
    fv1[s] = *(const f32x4*)(f2p + kc + c4*8 + 4);
    bv0[s] = *(const u16x8*)(Bb + (long)r4*NE_ + kc + c4*8);
    bv1[s] = *(const u16x8*)(Bb + (long)(64+r4)*NE_ + kc + c4*8);
  };
  auto commit = [&](int s, int buf) {
    u16x8 av;
    #pragma unroll
    for (int j = 0; j < 8; ++j) {
      unsigned int bit = (ab[s] >> j) & 1u;
      float z = f1r + ((j < 4) ? fv0[s][j] : fv1[s][j-4]);
      z = (z >= 0.f) ? z : ALPHA_ * z;
      float wt = bit ? __expf(z) : 0.f;
      unsigned short us = f2b(wt);
      av[j] = us; dot += bfu(us);
    }
    *(u16x8*)&SM[buf*2048 + r4*32 + swz(r4,c4)*8] = av;
    *(u16x8*)&SM[4096 + buf*4096 + r4*32 + swz(r4,c4)*8] = bv0[s];
    *(u16x8*)&SM[4096 + buf*4096 + (64+r4)*32 + swz(64+r4,c4)*8] = bv1[s];
  };

  const int NIT = NE_/32;
  stage(0, 0);
  stage(32, 1);
  commit(0, 0);
  int cur = 0;
  for (int it = 0; it < NIT; ++it) {
    __syncthreads();
    if (it+2 < NIT) stage((it+2)*32, it & 1);
    const unsigned short* AsB = &SM[cur*2048];
    const unsigned short* BsB = &SM[4096 + cur*4096];
    bf16x8 af[2], bfr[4];
    #pragma unroll
    for (int mt = 0; mt < 2; ++mt) {
      int r = wm*32 + mt*16 + lr;
      af[mt] = *(const bf16x8*)&AsB[r*32 + swz(r,g)*8];
    }
    #pragma unroll
    for (int nt = 0; nt < 4; ++nt) {
      int n = wn*64 + nt*16 + lr;
      bfr[nt] = *(const bf16x8*)&BsB[n*32 + swz(n,g)*8];
    }
    #pragma unroll
    for (int mt = 0; mt < 2; ++mt)
      #pragma unroll
      for (int nt = 0; nt < 4; ++nt)
        acc[mt][nt] = __builtin_amdgcn_mfma_f32_16x16x32_bf16(af[mt], bfr[nt], acc[mt][nt], 0, 0, 0);
    if (it+1 < NIT) { commit((it+1) & 1, cur^1); cur ^= 1; }
  }
  dot += __shfl_down(dot, 2, 4); dot += __shfl_down(dot, 1, 4);
  if ((lane & 3) == 0) dsum[r4] = dot;
  if (EPI == 2 && t < 128) colsum[t] = 0.f;
  __syncthreads();

  if (EPI == 1) {
    // x2 = elu(node) -> LDS U[64][136]
    #pragma unroll
    for (int mt = 0; mt < 2; ++mt)
      #pragma unroll
      for (int nt = 0; nt < 4; ++nt) {
        int col = wn*64 + nt*16 + lr;
        #pragma unroll
        for (int q = 0; q < 4; ++q) {
          int rl = wm*32 + mt*16 + g*4 + q;
          float v = acc[mt][nt][q] / dsum[rl];
          v = (v > 0.f) ? v : expm1f(v);
          SM[rl*136 + col] = f2b(v);
        }
      }
    __syncthreads();
    // fused layer-2 proj: row dots with ce1_2/cf1_2
    {
      const float* ce1 = consts + 384;
      const float* cf1 = consts + 512;
      int r = t >> 2, h0 = (t & 3) * 32;
      float p1 = 0.f, p2 = 0.f;
      #pragma unroll
      for (int j = 0; j < 32; ++j) {
        float xv = bfu(SM[r*136 + h0 + j]);
        p1 += xv * ce1[h0 + j];
        p2 += xv * cf1[h0 + j];
      }
      p1 += __shfl_down(p1, 2, 4); p1 += __shfl_down(p1, 1, 4);
      p2 += __shfl_down(p2, 2, 4); p2 += __shfl_down(p2, 1, 4);
      if ((t & 3) == 0) {
        float z = p1 + consts[769];
        z = (z >= 0.f) ? z : ALPHA_ * z;
        float wv = __expf(z);
        wrow[r] = wv;
        w1o[(long)b*NN_ + m0 + r] = wv;
        f1o[(long)b*NN_ + m0 + r] = p2;
      }
    }
    __syncthreads();
    // YT[b][h][n] = bf16(w1*x2) transposed write
    {
      int h = t >> 1, nh = (t & 1) * 32;
      unsigned short* dst = YTout + ((long)b*HID_ + h)*NN_ + m0 + nh;
      #pragma unroll
      for (int j = 0; j < 32; j += 8) {
        u16x8 o;
        #pragma unroll
        for (int k = 0; k < 8; ++k) {
          int rr = nh + j + k;
          o[k] = f2b(wrow[rr] * bfu(SM[rr*136 + h]));
        }
        *(u16x8*)&dst[j] = o;
      }
    }
  } else {
    float psum[4] = {0.f, 0.f, 0.f, 0.f};
    #pragma unroll
    for (int mt = 0; mt < 2; ++mt)
      #pragma unroll
      for (int q = 0; q < 4; ++q) {
        int rl = wm*32 + mt*16 + g*4 + q;
        float wc = wcount[(long)b*NN_ + m0 + rl];
        float inv = wc / dsum[rl];
        #pragma unroll
        for (int nt = 0; nt < 4; ++nt) psum[nt] += inv * acc[mt][nt][q];
      }
    #pragma unroll
    for (int nt = 0; nt < 4; ++nt) atomicAdd(&colsum[wn*64 + nt*16 + lr], psum[nt]);
    __syncthreads();
    if (t < 128) atomicAdd(&pooled[(long)b*HID_ + t], colsum[t]);
  }
}

__global__ void k_ln(const float* __restrict__ pooled, const float* __restrict__ msum,
                     const float* __restrict__ ln_g, const float* __restrict__ ln_b,
                     float* __restrict__ out)
{
  int b = blockIdx.x, t = threadIdx.x;   // 128
  __shared__ float sr[2];
  float bv = pooled[b*HID_ + t] / msum[b];
  int lane = t & 63;
  float p = bv;
  #pragma unroll
  for (int s = 32; s > 0; s >>= 1) p += __shfl_xor(p, s);
  if (lane == 0) sr[t >> 6] = p;
  __syncthreads();
  float mu = (sr[0] + sr[1]) * (1.f / HID_);
  float dv = bv - mu;
  p = dv * dv;
  #pragma unroll
  for (int s = 32; s > 0; s >>= 1) p += __shfl_xor(p, s);
  __syncthreads();
  if (lane == 0) sr[t >> 6] = p;
  __syncthreads();
  float var = (sr[0] + sr[1]) * (1.f / HID_);
  out[b*HID_ + t] = dv / sqrtf(var + 1e-6f) * ln_g[t] + ln_b[t];
}

extern "C" void kernel_launch(void* const* d_in, const int* in_sizes, int n_in,
                              void* d_out, int out_size, void* d_ws, size_t ws_size,
                              hipStream_t stream)
{
  const int*   items = (const int*)d_in[0];
  const int*   alias = (const int*)d_in[1];
  const float* masks = (const float*)d_in[2];
  const float* adj   = (const float*)d_in[3];
  const float* emb   = (const float*)d_in[4];
  const float* w2_1  = (const float*)d_in[5];
  const float* w3_1  = (const float*)d_in[6];
  const float* a_1   = (const float*)d_in[7];
  const float* a2_1  = (const float*)d_in[8];
  const float* wc_1  = (const float*)d_in[9];
  const float* w_2   = (const float*)d_in[10];
  const float* w2_2  = (const float*)d_in[11];
  const float* w3_2  = (const float*)d_in[12];
  const float* a_2   = (const float*)d_in[13];
  const float* a2_2  = (const float*)d_in[14];
  const float* wc_2  = (const float*)d_in[15];
  const float* ln_g  = (const float*)d_in[16];
  const float* ln_b  = (const float*)d_in[17];
  float* out = (float*)d_out;

  char* ws = (char*)d_ws;
  size_t off = 0;
  auto alloc = [&](size_t bytes) -> void* {
    void* p = ws + off; off += (bytes + 255) / 256 * 256; return p;
  };
  unsigned long long* ADJBb = (unsigned long long*)alloc((size_t)B_*NE_*(NN_/8));
  unsigned short*     ADJT16= (unsigned short*)    alloc((size_t)B_*NN_*(NE_/8));
  unsigned short* YT   = (unsigned short*)alloc((size_t)B_*HID_*NN_*2);
  unsigned short* ET   = (unsigned short*)alloc((size_t)B_*HID_*NE_*2);
  float* wcount= (float*)alloc((size_t)B_*NN_*4);
  float* pooled= (float*)alloc((size_t)B_*HID_*4);
  float* w1L1  = (float*)alloc((size_t)B_*NN_*4);
  float* f1L1  = (float*)alloc((size_t)B_*NN_*4);
  float* w1L2  = (float*)alloc((size_t)B_*NN_*4);
  float* f1L2  = (float*)alloc((size_t)B_*NN_*4);
  float* f2    = (float*)alloc((size_t)B_*NE_*4);
  float* msum  = (float*)alloc(B_*4);
  float* consts= (float*)alloc(772*4);
  unsigned short* W2T = (unsigned short*)alloc((size_t)HID_*HID_*2);
  if (off > ws_size) return;

  // ---------------- front-end ----------------
  k_small<<<74, 256, 0, stream>>>(w2_1, w3_1, a_1, a2_1, wc_1, w2_2, w3_2, a_2, a2_2, wc_2,
                                  w_2, alias, masks, consts, W2T, wcount, msum, pooled);
  k_prep<<<B_*16, 256, 0, stream>>>(adj, ADJBb, ADJT16);
  k_fproj<<<dim3(NN_/64, B_), 256, 0, stream>>>(emb, items, consts, w1L1, f1L1, YT);

  // ---------------- layer 1 ----------------
  k_gemm_edge<0><<<B_*(NE_/64), 256, 0, stream>>>((const unsigned char*)ADJBb, YT, w1L1,
        consts, 0, W2T, ET, f2);
  k_gemm_att<1><<<B_*(NN_/64), 256, 0, stream>>>((const unsigned char*)ADJT16, ET, f1L1, f2,
        consts, YT, w1L2, f1L2, nullptr, nullptr);

  // ---------------- layer 2 ----------------
  k_gemm_edge<1><<<B_*(NE_/64), 256, 0, stream>>>((const unsigned char*)ADJBb, YT, w1L2,
        consts, 1, W2T, ET, f2);
  k_gemm_att<2><<<B_*(NN_/64), 256, 0, stream>>>((const unsigned char*)ADJT16, ET, f1L2, f2,
        consts, nullptr, nullptr, nullptr, wcount, pooled);

  // ---------------- layernorm ----------------
  k_ln<<<B_, HID_, 0, stream>>>(pooled, msum, ln_g, ln_b, out);
}